// Round 4
// baseline (252.337 us; speedup 1.0000x reference)
//
#include <hip/hip_runtime.h>

// Parametric Multichannel Wiener Filter, MI355X single fused kernel.
// B=4, C=8, F=512, T=1000. One block per (b,f): 2048 blocks x 256 threads.
// LDS = 65,064 B (<= 64 KiB static limit) -> 2 blocks/CU.
// Output: harness stores the REAL PART of the complex reference as float32
// (out_size = B*C*F*T = 16,384,000). Fallback float2 path if out_size is 2x.

#define NB 4
#define NC 8
#define NF 512
#define NT 1000

__global__ __launch_bounds__(256, 2) void pmwf_kernel(
    const float* __restrict__ xre, const float* __restrict__ xim,
    const float* __restrict__ msk_s, const float* __restrict__ msk_n,
    float* __restrict__ out, int real_only)
{
    __shared__ float2 xs[NC * NT];     // x as (re,im) per (c,t)   64000 B
    __shared__ float2 M[8][16];        // augmented [A|B]; later cols 0..7 hold G
    __shared__ float2 invs;            // (1/sum_s, 1/sum_n)
    __shared__ float2 redscr[4];       // per-wave mask partial sums

    const int tid = threadIdx.x;
    const int bid = blockIdx.x;
    const int b = bid >> 9;      // /512
    const int f = bid & 511;

    const size_t mbase = ((size_t)b * NF + f) * NT;

    // ---------------- load x into LDS; mask sums from global ----------------
    float2 psum = make_float2(0.f, 0.f);
    if (tid < 250) {
        const int t0 = tid * 4;
        float4 s4 = *(const float4*)(msk_s + mbase + t0);
        float4 n4 = *(const float4*)(msk_n + mbase + t0);
        psum.x = s4.x + s4.y + s4.z + s4.w;
        psum.y = n4.x + n4.y + n4.z + n4.w;
#pragma unroll
        for (int c = 0; c < NC; ++c) {
            const size_t xb = (((size_t)b * NC + c) * NF + f) * NT + t0;
            float4 r4 = *(const float4*)(xre + xb);
            float4 i4 = *(const float4*)(xim + xb);
            float2* xp = &xs[c * NT + t0];
            xp[0] = make_float2(r4.x, i4.x);
            xp[1] = make_float2(r4.y, i4.y);
            xp[2] = make_float2(r4.z, i4.z);
            xp[3] = make_float2(r4.w, i4.w);
        }
    }
    // reduce mask sums: wave shuffle + tiny LDS combine
#pragma unroll
    for (int d = 1; d < 64; d <<= 1) {
        psum.x += __shfl_xor(psum.x, d);
        psum.y += __shfl_xor(psum.y, d);
    }
    if ((tid & 63) == 0) redscr[tid >> 6] = psum;
    __syncthreads();
    if (tid == 0) {
        float ss = redscr[0].x + redscr[1].x + redscr[2].x + redscr[3].x;
        float sn = redscr[0].y + redscr[1].y + redscr[2].y + redscr[3].y;
        invs = make_float2(1.f / (ss + 1e-10f), 1.f / (sn + 1e-10f));
    }
    __syncthreads();

    // ---------------- PSD accumulation ----------------
    // thread = (pair, chunk): pair=tid>>2 in [0,64), chunk=tid&3 (lane bits 0..1)
    {
        const int pair = tid >> 2;
        const int chunk = tid & 3;
        const int pc = pair >> 3, pe = pair & 7;
        const float2* xcp = &xs[pc * NT + chunk * 250];
        const float2* xep = &xs[pe * NT + chunk * 250];
        const float* msp = msk_s + mbase + chunk * 250;   // L1-hot, 4 addrs/wave
        const float* mnp = msk_n + mbase + chunk * 250;
        float sre = 0.f, sim = 0.f, nre = 0.f, nim = 0.f;
#pragma unroll 5
        for (int i = 0; i < 250; ++i) {
            float2 a = xcp[i];
            float2 e = xep[i];
            float ms = msp[i];
            float mn = mnp[i];
            // a * conj(e)
            float pr = a.x * e.x + a.y * e.y;
            float pi = a.y * e.x - a.x * e.y;
            sre += ms * pr; sim += ms * pi;
            nre += mn * pr; nim += mn * pi;
        }
        // cross-chunk reduce (chunk bits are lane bits 0,1)
        sre += __shfl_xor(sre, 1); sre += __shfl_xor(sre, 2);
        sim += __shfl_xor(sim, 1); sim += __shfl_xor(sim, 2);
        nre += __shfl_xor(nre, 1); nre += __shfl_xor(nre, 2);
        nim += __shfl_xor(nim, 1); nim += __shfl_xor(nim, 2);
        if (chunk == 0) {
            float2 iv = invs;
            M[pc][pe]     = make_float2(nre * iv.y, nim * iv.y);  // A = psd_n
            M[pc][pe + 8] = make_float2(sre * iv.x, sim * iv.x);  // B = psd_s
        }
    }
    __syncthreads();

    // ---------------- diagonal regularization ----------------
    float dreg;
    {
        float trn = 0.f;
#pragma unroll
        for (int k = 0; k < 8; ++k) trn += M[k][k].x;
        dreg = 1e-6f * trn + 1e-8f;
    }
    __syncthreads();
    if (tid < 8) M[tid][tid].x += dreg;
    __syncthreads();

    // ---------------- Gauss-Jordan: [A|B] -> [I|A^-1 B] ----------------
    {
        const int r = tid >> 4, jc = tid & 15;
        const bool act = tid < 128;
#pragma unroll
        for (int k = 0; k < 8; ++k) {
            float2 newkj;
            if (act && r == k) {
                float2 p = M[k][k];
                float ip = 1.f / (p.x * p.x + p.y * p.y);
                float2 v = M[k][jc];
                newkj = make_float2((v.x * p.x + v.y * p.y) * ip,
                                    (v.y * p.x - v.x * p.y) * ip);
            }
            __syncthreads();
            if (act && r == k) M[k][jc] = newkj;
            __syncthreads();
            float2 fr, pv, cur;
            if (act) { fr = M[r][k]; pv = M[k][jc]; cur = M[r][jc]; }
            __syncthreads();
            if (act && r != k) {
                M[r][jc] = make_float2(cur.x - (fr.x * pv.x - fr.y * pv.y),
                                       cur.y - (fr.x * pv.y + fr.y * pv.x));
            }
            __syncthreads();
        }
    }

    // ---------------- W = X/(1+tr); overlay G[m][c]=conj(W[c][m]) into M[m][c] ----
    {
        float2 tr = make_float2(1.f, 0.f);   // BETA + trace(num)
#pragma unroll
        for (int k = 0; k < 8; ++k) { tr.x += M[k][k + 8].x; tr.y += M[k][k + 8].y; }
        float id = 1.f / (tr.x * tr.x + tr.y * tr.y);
        float2 invd = make_float2(tr.x * id, -tr.y * id);
        if (tid < 64) {
            int m = tid & 7, c = tid >> 3;
            float2 v = M[c][m + 8];          // read cols 8..15
            // W = v*invd ; G = conj(W)  -> write cols 0..7 (disjoint, race-free)
            M[m][c] = make_float2(v.x * invd.x - v.y * invd.y,
                                  -(v.x * invd.y + v.y * invd.x));
        }
    }
    __syncthreads();

    // ---------------- apply: out[m][t] = sum_c G[m][c] * x[c][t] ----------------
    {
        const size_t obase = ((size_t)b * NC * NF + f) * NT;  // (b,m,f,t) flat, m stride NF*NT
        if (real_only) {
            // store Re(out) only, float32, contiguous in t
            for (int t = tid; t < NT; t += 256) {
                float2 xv[8];
#pragma unroll
                for (int c = 0; c < 8; ++c) xv[c] = xs[c * NT + t];
#pragma unroll
                for (int m = 0; m < 8; ++m) {
                    float ar = 0.f;
#pragma unroll
                    for (int c2 = 0; c2 < 8; ++c2) {
                        float2 g = M[m][c2];     // G lives in cols 0..7 of M
                        float2 v = xv[c2];
                        ar += g.x * v.x - g.y * v.y;
                    }
                    out[obase + (size_t)m * NF * NT + t] = ar;
                }
            }
        } else {
            // interleaved complex64 fallback
            float2* outc = (float2*)out;
            for (int t = tid; t < NT; t += 256) {
                float2 xv[8];
#pragma unroll
                for (int c = 0; c < 8; ++c) xv[c] = xs[c * NT + t];
#pragma unroll
                for (int m = 0; m < 8; ++m) {
                    float ar = 0.f, ai = 0.f;
#pragma unroll
                    for (int c2 = 0; c2 < 8; ++c2) {
                        float2 g = M[m][c2];
                        float2 v = xv[c2];
                        ar += g.x * v.x - g.y * v.y;
                        ai += g.x * v.y + g.y * v.x;
                    }
                    outc[obase + (size_t)m * NF * NT + t] = make_float2(ar, ai);
                }
            }
        }
    }
}

extern "C" void kernel_launch(void* const* d_in, const int* in_sizes, int n_in,
                              void* d_out, int out_size, void* d_ws, size_t ws_size,
                              hipStream_t stream) {
    const float* xre = (const float*)d_in[0];
    const float* xim = (const float*)d_in[1];
    const float* ms  = (const float*)d_in[2];
    const float* mn  = (const float*)d_in[3];
    // out_size == B*C*F*T      (16,384,000) -> real-part-only float32 layout
    // out_size == 2*B*C*F*T    (32,768,000) -> interleaved complex64 layout
    const int real_only = (out_size < 2 * NB * NC * NF * NT) ? 1 : 0;
    hipLaunchKernelGGL(pmwf_kernel, dim3(NB * NF), dim3(256), 0, stream,
                       xre, xim, ms, mn, (float*)d_out, real_only);
}